// Round 1
// baseline (297.997 us; speedup 1.0000x reference)
//
#include <hip/hip_runtime.h>
#include <stdint.h>

#define BB 8
#define NN 2048
#define DD 128

typedef unsigned long long ull;

// insertion into sorted-ascending 8-slot register array (static indices only)
#define INS8(t8, cand) do { \
    t8[7] = (cand); ull _t; \
    if (t8[7] < t8[6]) { _t = t8[6]; t8[6] = t8[7]; t8[7] = _t; } \
    if (t8[6] < t8[5]) { _t = t8[5]; t8[5] = t8[6]; t8[6] = _t; } \
    if (t8[5] < t8[4]) { _t = t8[4]; t8[4] = t8[5]; t8[5] = _t; } \
    if (t8[4] < t8[3]) { _t = t8[3]; t8[3] = t8[4]; t8[4] = _t; } \
    if (t8[3] < t8[2]) { _t = t8[2]; t8[2] = t8[3]; t8[3] = _t; } \
    if (t8[2] < t8[1]) { _t = t8[1]; t8[1] = t8[2]; t8[2] = _t; } \
    if (t8[1] < t8[0]) { _t = t8[0]; t8[0] = t8[1]; t8[1] = _t; } \
  } while (0)

// ---------------- Kernel 1: xx[row] = sum_d x^2 ----------------
__global__ __launch_bounds__(256) void k_xx(const float* __restrict__ x,
                                            float* __restrict__ xx) {
  int row  = blockIdx.x * 4 + (threadIdx.x >> 6);
  int lane = threadIdx.x & 63;
  float2 v = *reinterpret_cast<const float2*>(x + (size_t)row * DD + lane * 2);
  float p = v.x * v.x + v.y * v.y;
  #pragma unroll
  for (int off = 1; off < 64; off <<= 1) p += __shfl_xor(p, off);
  if (lane == 0) xx[row] = p;
}

// ---------------- Kernel 2: dual GEMM  s = x@Ws, y = x@Wn ----------------
// hbase = s + y + bias stored; y stored separately for the gather.
__global__ __launch_bounds__(256) void k_gemm(const float* __restrict__ x,
                                              const float* __restrict__ Ws,
                                              const float* __restrict__ Wn,
                                              const float* __restrict__ bias,
                                              float* __restrict__ hbase,
                                              float* __restrict__ y) {
  __shared__ __align__(16) float xt[128 * 64];    // [k][r]
  __shared__ __align__(16) float wt[128 * 128];   // [k][c]
  int tid = threadIdx.x;
  size_t r0 = (size_t)blockIdx.x * 64;

  { // stage x transposed
    int rr = tid >> 2, kp = (tid & 3) << 5;
    const float* src = x + (r0 + rr) * DD + kp;
    #pragma unroll
    for (int q = 0; q < 8; ++q) {
      float4 v = *(const float4*)(src + (q << 2));
      int k = kp + (q << 2);
      xt[(k + 0) * 64 + rr] = v.x; xt[(k + 1) * 64 + rr] = v.y;
      xt[(k + 2) * 64 + rr] = v.z; xt[(k + 3) * 64 + rr] = v.w;
    }
  }
  { // stage Ws (row-major copy)
    const float4* s4 = (const float4*)Ws;
    float4* w4 = (float4*)wt;
    #pragma unroll
    for (int q = 0; q < 16; ++q) w4[q * 256 + tid] = s4[q * 256 + tid];
  }
  __syncthreads();

  int tc = tid & 15, tr = tid >> 4;
  float accS[4][8], accY[4][8];
  #pragma unroll
  for (int i = 0; i < 4; ++i)
    #pragma unroll
    for (int u = 0; u < 8; ++u) { accS[i][u] = 0.f; accY[i][u] = 0.f; }

  #pragma unroll 2
  for (int k = 0; k < 128; ++k) {
    float4 a4 = *(const float4*)(xt + k * 64 + (tr << 2));
    float4 w0 = *(const float4*)(wt + k * 128 + (tc << 3));
    float4 w1 = *(const float4*)(wt + k * 128 + (tc << 3) + 4);
    float aa[4] = {a4.x, a4.y, a4.z, a4.w};
    float ww[8] = {w0.x, w0.y, w0.z, w0.w, w1.x, w1.y, w1.z, w1.w};
    #pragma unroll
    for (int i = 0; i < 4; ++i)
      #pragma unroll
      for (int u = 0; u < 8; ++u) accS[i][u] = fmaf(aa[i], ww[u], accS[i][u]);
  }
  __syncthreads();
  { // stage Wn
    const float4* s4 = (const float4*)Wn;
    float4* w4 = (float4*)wt;
    #pragma unroll
    for (int q = 0; q < 16; ++q) w4[q * 256 + tid] = s4[q * 256 + tid];
  }
  __syncthreads();
  #pragma unroll 2
  for (int k = 0; k < 128; ++k) {
    float4 a4 = *(const float4*)(xt + k * 64 + (tr << 2));
    float4 w0 = *(const float4*)(wt + k * 128 + (tc << 3));
    float4 w1 = *(const float4*)(wt + k * 128 + (tc << 3) + 4);
    float aa[4] = {a4.x, a4.y, a4.z, a4.w};
    float ww[8] = {w0.x, w0.y, w0.z, w0.w, w1.x, w1.y, w1.z, w1.w};
    #pragma unroll
    for (int i = 0; i < 4; ++i)
      #pragma unroll
      for (int u = 0; u < 8; ++u) accY[i][u] = fmaf(aa[i], ww[u], accY[i][u]);
  }

  float4 bv0 = *(const float4*)(bias + (tc << 3));
  float4 bv1 = *(const float4*)(bias + (tc << 3) + 4);
  float bb[8] = {bv0.x, bv0.y, bv0.z, bv0.w, bv1.x, bv1.y, bv1.z, bv1.w};
  #pragma unroll
  for (int i = 0; i < 4; ++i) {
    size_t row = r0 + (tr << 2) + i;
    float h[8];
    #pragma unroll
    for (int u = 0; u < 8; ++u) h[u] = (accS[i][u] + accY[i][u]) + bb[u];
    *(float4*)(y + row * DD + (tc << 3))     = make_float4(accY[i][0], accY[i][1], accY[i][2], accY[i][3]);
    *(float4*)(y + row * DD + (tc << 3) + 4) = make_float4(accY[i][4], accY[i][5], accY[i][6], accY[i][7]);
    *(float4*)(hbase + row * DD + (tc << 3))     = make_float4(h[0], h[1], h[2], h[3]);
    *(float4*)(hbase + row * DD + (tc << 3) + 4) = make_float4(h[4], h[5], h[6], h[7]);
  }
}

// ---------------- Kernel 3: pairwise dist + 8-NN selection ----------------
// grid 256 = 8 batches x 32 n-tiles(64). block 512 (8 waves).
// per m-tile(128): reg-prefetch B, transpose to LDS, 4x4 register-tile f32 GEMM,
// dist to LDS, 8 scanners/row maintain packed (dist,idx) top-8, merge at end.
__global__ __launch_bounds__(512) void k_knn(const float* __restrict__ x,
                                             const float* __restrict__ xx,
                                             int* __restrict__ nbr) {
  __shared__ __align__(16) float At[128 * 64];    // [k][n]
  __shared__ __align__(16) float Bt[128 * 132];   // [k][m] padded
  __shared__ __align__(16) float Dd[64 * 132];    // [n][m] padded (aliased for merge)
  __shared__ float xxn[64];
  __shared__ float xxm[128];

  int tid = threadIdx.x;
  int b  = blockIdx.x >> 5;
  int n0 = (blockIdx.x & 31) << 6;
  const float* xb  = x  + ((size_t)b << 11) * DD;
  const float* xxb = xx + ((size_t)b << 11);

  { // stage A transposed (once)
    int rr = tid >> 3, kp = (tid & 7) << 4;
    const float* src = xb + (size_t)(n0 + rr) * DD + kp;
    #pragma unroll
    for (int q = 0; q < 4; ++q) {
      float4 v = *(const float4*)(src + (q << 2));
      int k = kp + (q << 2);
      At[(k + 0) * 64 + rr] = v.x; At[(k + 1) * 64 + rr] = v.y;
      At[(k + 2) * 64 + rr] = v.z; At[(k + 3) * 64 + rr] = v.w;
    }
  }
  if (tid < 64) xxn[tid] = xxb[n0 + tid];

  int tc = tid & 31, tr = tid >> 5;        // compute role: 4 cols x 4 rows
  int scan_row = tid >> 3, scan_j = tid & 7;  // scan role: 8 scanners/row
  int my_n = n0 + scan_row;
  int mrr = tid >> 2, mkp = (tid & 3) << 5;   // staging role

  ull t8[8];
  #pragma unroll
  for (int q = 0; q < 8; ++q) t8[q] = ~0ull;

  for (int mt = 0; mt < 16; ++mt) {
    int m0 = mt << 7;
    // (1) global prefetch into registers (no LDS)
    float4 breg[8];
    const float* bsrc = xb + (size_t)(m0 + mrr) * DD + mkp;
    #pragma unroll
    for (int q = 0; q < 8; ++q) breg[q] = *(const float4*)(bsrc + (q << 2));
    float xmreg = 0.f;
    if (tid < 128) xmreg = xxb[m0 + tid];

    __syncthreads();   // prev compute (Bt) and prev scan (Dd) finished
    // (3) transpose-store B tile
    #pragma unroll
    for (int q = 0; q < 8; ++q) {
      int k = mkp + (q << 2);
      Bt[(k + 0) * 132 + mrr] = breg[q].x; Bt[(k + 1) * 132 + mrr] = breg[q].y;
      Bt[(k + 2) * 132 + mrr] = breg[q].z; Bt[(k + 3) * 132 + mrr] = breg[q].w;
    }
    if (tid < 128) xxm[tid] = xmreg;
    __syncthreads();   // Bt ready

    // (5) 4x4 register-tile dot products over K=128
    float acc[4][4];
    #pragma unroll
    for (int i = 0; i < 4; ++i)
      #pragma unroll
      for (int u = 0; u < 4; ++u) acc[i][u] = 0.f;
    #pragma unroll 4
    for (int k = 0; k < 128; ++k) {
      float4 a4 = *(const float4*)(At + k * 64 + (tr << 2));
      float4 b4 = *(const float4*)(Bt + k * 132 + (tc << 2));
      float aa[4] = {a4.x, a4.y, a4.z, a4.w};
      float bv[4] = {b4.x, b4.y, b4.z, b4.w};
      #pragma unroll
      for (int i = 0; i < 4; ++i)
        #pragma unroll
        for (int u = 0; u < 4; ++u) acc[i][u] = fmaf(aa[i], bv[u], acc[i][u]);
    }
    // (6) dist = (xx_n - 2*dot) + xx_m, clipped; write to Dd
    float xnv[4], xmv[4];
    #pragma unroll
    for (int i = 0; i < 4; ++i) xnv[i] = xxn[(tr << 2) + i];
    #pragma unroll
    for (int u = 0; u < 4; ++u) xmv[u] = xxm[(tc << 2) + u];
    #pragma unroll
    for (int i = 0; i < 4; ++i) {
      float4 dv;
      dv.x = fmaxf((xnv[i] - 2.f * acc[i][0]) + xmv[0], 0.f);
      dv.y = fmaxf((xnv[i] - 2.f * acc[i][1]) + xmv[1], 0.f);
      dv.z = fmaxf((xnv[i] - 2.f * acc[i][2]) + xmv[2], 0.f);
      dv.w = fmaxf((xnv[i] - 2.f * acc[i][3]) + xmv[3], 0.f);
      *(float4*)(Dd + ((tr << 2) + i) * 132 + (tc << 2)) = dv;
    }
    __syncthreads();   // Dd ready

    // (8) scan 16 candidates into private top-8 (packed u64: dist bits | idx)
    const float* drow = Dd + scan_row * 132 + (scan_j << 4);
    #pragma unroll
    for (int t = 0; t < 16; ++t) {
      float d = drow[t];
      int mg = m0 + (scan_j << 4) + t;
      ull cand = (((ull)__float_as_uint(d)) << 32) | (unsigned)mg;
      if (mg != my_n && cand < t8[7]) INS8(t8, cand);
    }
  }

  __syncthreads();
  ull* mbuf = (ull*)Dd;  // 64*8 lists * 8 u64 = 32 KB <= Dd
  #pragma unroll
  for (int q = 0; q < 8; ++q) mbuf[((scan_row << 3) + scan_j) * 8 + q] = t8[q];
  __syncthreads();
  if (scan_j == 0) {
    for (int j = 1; j < 8; ++j) {
      #pragma unroll
      for (int q = 0; q < 8; ++q) {
        ull cand = mbuf[((scan_row << 3) + j) * 8 + q];
        if (cand < t8[7]) INS8(t8, cand);
      }
    }
    int* op = nbr + (((size_t)b << 11) + my_n) * 8;
    #pragma unroll
    for (int q = 0; q < 8; ++q) op[q] = (int)(t8[q] & 0xffffffffu);
  }
}

// ---------------- Kernel 4: gather + KAN rational + BN partial sums ----------------
__global__ __launch_bounds__(256) void k_kan(const float* __restrict__ hbase,
                                             const float* __restrict__ y,
                                             const int* __restrict__ nbr,
                                             const float* __restrict__ kan_a,
                                             const float* __restrict__ kan_b,
                                             float* __restrict__ hkan,
                                             double* __restrict__ sums) {
  int f = threadIdx.x & 127;
  int half = threadIdx.x >> 7;
  int r0 = blockIdx.x * 16 + half * 8;
  float a0 = kan_a[f * 3 + 0], a1 = kan_a[f * 3 + 1], a2 = kan_a[f * 3 + 2];
  float b0 = kan_b[f * 2 + 0], b1 = kan_b[f * 2 + 1];
  // c = fl32(fl32((8+1e-6)^-0.5)^2), reference's uniform adj coefficient
  float disf = (float)(1.0 / sqrt((double)(8.0f + 1e-6f)));
  float cf = disf * disf;
  double sh = 0.0, sh2 = 0.0;
  #pragma unroll
  for (int i = 0; i < 8; ++i) {
    int r = r0 + i;
    int bb = r >> 11;
    const int* np_ = nbr + (size_t)r * 8;
    float t = 0.f;
    #pragma unroll
    for (int j = 0; j < 8; ++j) {
      int m = np_[j];
      float yv = y[((size_t)(bb << 11) + m) * DD + f];
      t = fmaf(cf, yv, t);
    }
    float h = hbase[(size_t)r * DD + f] + t;
    float h2 = h * h;
    float num = (a0 + a1 * h) + a2 * h2;
    float den = 1.0f + fabsf(b0 * h + b1 * h2);
    float hk = num / (den + 1e-8f);
    hkan[(size_t)r * DD + f] = hk;
    sh += (double)hk; sh2 += (double)hk * (double)hk;
  }
  atomicAdd(&sums[f], sh);
  atomicAdd(&sums[128 + f], sh2);
}

// ---------------- Kernel 5: BN finalize + normalize ----------------
__global__ __launch_bounds__(256) void k_bn(const float* __restrict__ hkan,
                                            const double* __restrict__ sums,
                                            const float* __restrict__ gamma,
                                            const float* __restrict__ beta,
                                            float* __restrict__ out) {
  __shared__ float mn[128], sc[128], bt[128];
  int tid = threadIdx.x;
  if (tid < 128) {
    double M = (double)(BB * NN);
    double mean = sums[tid] / M;
    double var = sums[128 + tid] / M - mean * mean;
    if (var < 0.0) var = 0.0;
    mn[tid] = (float)mean;
    sc[tid] = (float)(1.0 / sqrt(var + 1e-5)) * gamma[tid];
    bt[tid] = beta[tid];
  }
  __syncthreads();
  const int total4 = BB * NN * DD / 4;
  for (int i4 = blockIdx.x * blockDim.x + threadIdx.x; i4 < total4;
       i4 += gridDim.x * blockDim.x) {
    float4 v = ((const float4*)hkan)[i4];
    int fb = (i4 * 4) & 127;
    float4 o;
    o.x = (v.x - mn[fb + 0]) * sc[fb + 0] + bt[fb + 0];
    o.y = (v.y - mn[fb + 1]) * sc[fb + 1] + bt[fb + 1];
    o.z = (v.z - mn[fb + 2]) * sc[fb + 2] + bt[fb + 2];
    o.w = (v.w - mn[fb + 3]) * sc[fb + 3] + bt[fb + 3];
    ((float4*)out)[i4] = o;
  }
}

extern "C" void kernel_launch(void* const* d_in, const int* in_sizes, int n_in,
                              void* d_out, int out_size, void* d_ws, size_t ws_size,
                              hipStream_t stream) {
  const float* x     = (const float*)d_in[0];
  const float* Ws    = (const float*)d_in[1];
  const float* Wn    = (const float*)d_in[2];
  const float* ka    = (const float*)d_in[3];
  const float* kb    = (const float*)d_in[4];
  const float* bias  = (const float*)d_in[5];
  const float* gamma = (const float*)d_in[6];
  const float* beta  = (const float*)d_in[7];
  float* out = (float*)d_out;

  char* ws = (char*)d_ws;
  float*  xx    = (float*)(ws + 0);          //  64 KB
  int*    nbr   = (int*)(ws + 65536);        // 512 KB
  double* sums  = (double*)(ws + 589824);    //   2 KB
  float*  y     = (float*)(ws + 1048576);    //   8 MB
  float*  hbase = (float*)(ws + 9437184);    //   8 MB
  float*  hkan  = (float*)(ws + 17825792);   //   8 MB

  hipMemsetAsync(sums, 0, 256 * sizeof(double), stream);
  k_xx  <<<4096, 256, 0, stream>>>(x, xx);
  k_gemm<<<256,  256, 0, stream>>>(x, Ws, Wn, bias, hbase, y);
  k_knn <<<256,  512, 0, stream>>>(x, xx, nbr);
  k_kan <<<1024, 256, 0, stream>>>(hbase, y, nbr, ka, kb, hkan, sums);
  k_bn  <<<1024, 256, 0, stream>>>(hkan, sums, gamma, beta, out);
}

// Round 2
// 284.329 us; speedup vs baseline: 1.0481x; 1.0481x over previous
//
#include <hip/hip_runtime.h>
#include <stdint.h>

#define BB 8
#define NN 2048
#define DD 128

typedef unsigned long long ull;

// insertion into sorted-ascending 8-slot register array (static indices only)
#define INS8(t8, cand) do { \
    t8[7] = (cand); ull _t; \
    if (t8[7] < t8[6]) { _t = t8[6]; t8[6] = t8[7]; t8[7] = _t; } \
    if (t8[6] < t8[5]) { _t = t8[5]; t8[5] = t8[6]; t8[6] = _t; } \
    if (t8[5] < t8[4]) { _t = t8[4]; t8[4] = t8[5]; t8[5] = _t; } \
    if (t8[4] < t8[3]) { _t = t8[3]; t8[3] = t8[4]; t8[4] = _t; } \
    if (t8[3] < t8[2]) { _t = t8[2]; t8[2] = t8[3]; t8[3] = _t; } \
    if (t8[2] < t8[1]) { _t = t8[1]; t8[1] = t8[2]; t8[2] = _t; } \
    if (t8[1] < t8[0]) { _t = t8[0]; t8[0] = t8[1]; t8[1] = _t; } \
  } while (0)

// ---------------- Kernel 1: xx[row] = sum_d x^2 ----------------
__global__ __launch_bounds__(256) void k_xx(const float* __restrict__ x,
                                            float* __restrict__ xx) {
  int row  = blockIdx.x * 4 + (threadIdx.x >> 6);
  int lane = threadIdx.x & 63;
  float2 v = *reinterpret_cast<const float2*>(x + (size_t)row * DD + lane * 2);
  float p = v.x * v.x + v.y * v.y;
  #pragma unroll
  for (int off = 1; off < 64; off <<= 1) p += __shfl_xor(p, off);
  if (lane == 0) xx[row] = p;
}

// ---------------- Kernel 2: dual GEMM  s = x@Ws, y = x@Wn ----------------
__global__ __launch_bounds__(256) void k_gemm(const float* __restrict__ x,
                                              const float* __restrict__ Ws,
                                              const float* __restrict__ Wn,
                                              const float* __restrict__ bias,
                                              float* __restrict__ hbase,
                                              float* __restrict__ y) {
  __shared__ __align__(16) float xt[128 * 64];    // [k][r]
  __shared__ __align__(16) float wt[128 * 128];   // [k][c]
  int tid = threadIdx.x;
  size_t r0 = (size_t)blockIdx.x * 64;

  { // stage x transposed
    int rr = tid >> 2, kp = (tid & 3) << 5;
    const float* src = x + (r0 + rr) * DD + kp;
    #pragma unroll
    for (int q = 0; q < 8; ++q) {
      float4 v = *(const float4*)(src + (q << 2));
      int k = kp + (q << 2);
      xt[(k + 0) * 64 + rr] = v.x; xt[(k + 1) * 64 + rr] = v.y;
      xt[(k + 2) * 64 + rr] = v.z; xt[(k + 3) * 64 + rr] = v.w;
    }
  }
  { // stage Ws (row-major copy)
    const float4* s4 = (const float4*)Ws;
    float4* w4 = (float4*)wt;
    #pragma unroll
    for (int q = 0; q < 16; ++q) w4[q * 256 + tid] = s4[q * 256 + tid];
  }
  __syncthreads();

  int tc = tid & 15, tr = tid >> 4;
  float accS[4][8], accY[4][8];
  #pragma unroll
  for (int i = 0; i < 4; ++i)
    #pragma unroll
    for (int u = 0; u < 8; ++u) { accS[i][u] = 0.f; accY[i][u] = 0.f; }

  #pragma unroll 2
  for (int k = 0; k < 128; ++k) {
    float4 a4 = *(const float4*)(xt + k * 64 + (tr << 2));
    float4 w0 = *(const float4*)(wt + k * 128 + (tc << 3));
    float4 w1 = *(const float4*)(wt + k * 128 + (tc << 3) + 4);
    float aa[4] = {a4.x, a4.y, a4.z, a4.w};
    float ww[8] = {w0.x, w0.y, w0.z, w0.w, w1.x, w1.y, w1.z, w1.w};
    #pragma unroll
    for (int i = 0; i < 4; ++i)
      #pragma unroll
      for (int u = 0; u < 8; ++u) accS[i][u] = fmaf(aa[i], ww[u], accS[i][u]);
  }
  __syncthreads();
  { // stage Wn
    const float4* s4 = (const float4*)Wn;
    float4* w4 = (float4*)wt;
    #pragma unroll
    for (int q = 0; q < 16; ++q) w4[q * 256 + tid] = s4[q * 256 + tid];
  }
  __syncthreads();
  #pragma unroll 2
  for (int k = 0; k < 128; ++k) {
    float4 a4 = *(const float4*)(xt + k * 64 + (tr << 2));
    float4 w0 = *(const float4*)(wt + k * 128 + (tc << 3));
    float4 w1 = *(const float4*)(wt + k * 128 + (tc << 3) + 4);
    float aa[4] = {a4.x, a4.y, a4.z, a4.w};
    float ww[8] = {w0.x, w0.y, w0.z, w0.w, w1.x, w1.y, w1.z, w1.w};
    #pragma unroll
    for (int i = 0; i < 4; ++i)
      #pragma unroll
      for (int u = 0; u < 8; ++u) accY[i][u] = fmaf(aa[i], ww[u], accY[i][u]);
  }

  float4 bv0 = *(const float4*)(bias + (tc << 3));
  float4 bv1 = *(const float4*)(bias + (tc << 3) + 4);
  float bb[8] = {bv0.x, bv0.y, bv0.z, bv0.w, bv1.x, bv1.y, bv1.z, bv1.w};
  #pragma unroll
  for (int i = 0; i < 4; ++i) {
    size_t row = r0 + (tr << 2) + i;
    float h[8];
    #pragma unroll
    for (int u = 0; u < 8; ++u) h[u] = (accS[i][u] + accY[i][u]) + bb[u];
    *(float4*)(y + row * DD + (tc << 3))     = make_float4(accY[i][0], accY[i][1], accY[i][2], accY[i][3]);
    *(float4*)(y + row * DD + (tc << 3) + 4) = make_float4(accY[i][4], accY[i][5], accY[i][6], accY[i][7]);
    *(float4*)(hbase + row * DD + (tc << 3))     = make_float4(h[0], h[1], h[2], h[3]);
    *(float4*)(hbase + row * DD + (tc << 3) + 4) = make_float4(h[4], h[5], h[6], h[7]);
  }
}

// ---------------- Kernel 3: pairwise dist + 8-NN selection ----------------
// grid 256 = 8 batches x 32 n-tiles(64). block 512 (8 waves).
// m-tile 256, k-chunked (32) Bt staging with register prefetch.
// thread tile 4n x 8m (32 FMA per 3 ds_read_b128).
__global__ __launch_bounds__(512) void k_knn(const float* __restrict__ x,
                                             const float* __restrict__ xx,
                                             int* __restrict__ nbr) {
  __shared__ __align__(16) float At[128 * 64];     // [k][n]        32.0 KB
  __shared__ __align__(16) float Bt[32 * 264];     // [k-chunk][m]  33.8 KB
  __shared__ __align__(16) float Dd[64 * 264];     // [n][m]        67.6 KB
  __shared__ float xxn[64];
  __shared__ float xxm[256];

  int tid = threadIdx.x;
  int b  = blockIdx.x >> 5;
  int n0 = (blockIdx.x & 31) << 6;
  const float* xb  = x  + ((size_t)b << 11) * DD;
  const float* xxb = xx + ((size_t)b << 11);

  { // stage A transposed: lane-per-row so writes hit consecutive banks (2-way only)
    int rr = tid & 63, kp = (tid >> 6) << 4;
    const float* src = xb + (size_t)(n0 + rr) * DD + kp;
    #pragma unroll
    for (int q = 0; q < 4; ++q) {
      float4 v = *(const float4*)(src + (q << 2));
      int k = kp + (q << 2);
      At[(k + 0) * 64 + rr] = v.x; At[(k + 1) * 64 + rr] = v.y;
      At[(k + 2) * 64 + rr] = v.z; At[(k + 3) * 64 + rr] = v.w;
    }
  }
  if (tid < 64) xxn[tid] = xxb[n0 + tid];

  int tc = tid & 31, tr = tid >> 5;            // compute: 32 col-grp x 16 row-grp
  int srow = tid >> 3, sj = tid & 7;           // scan: 8 scanners/row
  int my_n = n0 + srow;
  int mrr = tid >> 1, kq = (tid & 1) << 4;     // Bt staging: 2 threads/row

  ull t8[8];
  #pragma unroll
  for (int q = 0; q < 8; ++q) t8[q] = ~0ull;

  for (int mt = 0; mt < 8; ++mt) {
    int m0 = mt << 8;

    // prefetch chunk 0 + xxm into registers
    float4 bpre[4];
    {
      const float* bs = xb + (size_t)(m0 + mrr) * DD + kq;
      #pragma unroll
      for (int q = 0; q < 4; ++q) bpre[q] = *(const float4*)(bs + (q << 2));
    }
    float xmreg = 0.f;
    if (tid < 256) xmreg = xxb[m0 + tid];

    float acc[4][8];
    #pragma unroll
    for (int i = 0; i < 4; ++i)
      #pragma unroll
      for (int u = 0; u < 8; ++u) acc[i][u] = 0.f;

    for (int kc = 0; kc < 4; ++kc) {
      __syncthreads();   // prev compute done reading Bt (and prev scan done at kc==0)
      // write Bt chunk: per write step, wave's lanes are consecutive columns -> 2-way banks
      #pragma unroll
      for (int q = 0; q < 4; ++q) {
        int k = kq + (q << 2);
        Bt[(k + 0) * 264 + mrr] = bpre[q].x; Bt[(k + 1) * 264 + mrr] = bpre[q].y;
        Bt[(k + 2) * 264 + mrr] = bpre[q].z; Bt[(k + 3) * 264 + mrr] = bpre[q].w;
      }
      if (kc == 0 && tid < 256) xxm[tid] = xmreg;
      // issue next-chunk global loads (complete during compute)
      if (kc < 3) {
        const float* bs = xb + (size_t)(m0 + mrr) * DD + ((kc + 1) << 5) + kq;
        #pragma unroll
        for (int q = 0; q < 4; ++q) bpre[q] = *(const float4*)(bs + (q << 2));
      }
      __syncthreads();   // Bt ready

      const float* Abase = At + (kc << 5) * 64 + (tr << 2);
      #pragma unroll 4
      for (int k = 0; k < 32; ++k) {
        float4 a4 = *(const float4*)(Abase + k * 64);
        float4 b0 = *(const float4*)(Bt + k * 264 + (tc << 3));
        float4 b1 = *(const float4*)(Bt + k * 264 + (tc << 3) + 4);
        float aa[4] = {a4.x, a4.y, a4.z, a4.w};
        float bbv[8] = {b0.x, b0.y, b0.z, b0.w, b1.x, b1.y, b1.z, b1.w};
        #pragma unroll
        for (int i = 0; i < 4; ++i)
          #pragma unroll
          for (int u = 0; u < 8; ++u) acc[i][u] = fmaf(aa[i], bbv[u], acc[i][u]);
      }
    }

    // dist = (xx_n - 2*dot) + xx_m, clipped; write to Dd
    float4 xn4 = *(const float4*)(xxn + (tr << 2));
    float4 xm0 = *(const float4*)(xxm + (tc << 3));
    float4 xm1 = *(const float4*)(xxm + (tc << 3) + 4);
    float xnv[4] = {xn4.x, xn4.y, xn4.z, xn4.w};
    float xmv[8] = {xm0.x, xm0.y, xm0.z, xm0.w, xm1.x, xm1.y, xm1.z, xm1.w};
    #pragma unroll
    for (int i = 0; i < 4; ++i) {
      float4 d0, d1;
      d0.x = fmaxf((xnv[i] - 2.f * acc[i][0]) + xmv[0], 0.f);
      d0.y = fmaxf((xnv[i] - 2.f * acc[i][1]) + xmv[1], 0.f);
      d0.z = fmaxf((xnv[i] - 2.f * acc[i][2]) + xmv[2], 0.f);
      d0.w = fmaxf((xnv[i] - 2.f * acc[i][3]) + xmv[3], 0.f);
      d1.x = fmaxf((xnv[i] - 2.f * acc[i][4]) + xmv[4], 0.f);
      d1.y = fmaxf((xnv[i] - 2.f * acc[i][5]) + xmv[5], 0.f);
      d1.z = fmaxf((xnv[i] - 2.f * acc[i][6]) + xmv[6], 0.f);
      d1.w = fmaxf((xnv[i] - 2.f * acc[i][7]) + xmv[7], 0.f);
      int row = (tr << 2) + i;
      *(float4*)(Dd + row * 264 + (tc << 3))     = d0;
      *(float4*)(Dd + row * 264 + (tc << 3) + 4) = d1;
    }
    __syncthreads();   // Dd ready

    // scan: scanner sj reads cols sj + 8t  (bank = 8*row + sj + 8t -> 2-way, free)
    const float* dbase = Dd + srow * 264 + sj;
    #pragma unroll 8
    for (int t = 0; t < 32; ++t) {
      float d = dbase[t << 3];
      int mg = m0 + sj + (t << 3);
      ull cand = (((ull)__float_as_uint(d)) << 32) | (unsigned)mg;
      if (mg != my_n && cand < t8[7]) INS8(t8, cand);
    }
  }

  __syncthreads();
  ull* mbuf = (ull*)Dd;  // 64 rows * 8 lists * 8 u64 = 32 KB <= Dd
  #pragma unroll
  for (int q = 0; q < 8; ++q) mbuf[((srow << 3) + sj) * 8 + q] = t8[q];
  __syncthreads();
  if (sj == 0) {
    for (int j = 1; j < 8; ++j) {
      #pragma unroll
      for (int q = 0; q < 8; ++q) {
        ull cand = mbuf[((srow << 3) + j) * 8 + q];
        if (cand < t8[7]) INS8(t8, cand);
      }
    }
    int* op = nbr + (((size_t)b << 11) + my_n) * 8;
    #pragma unroll
    for (int q = 0; q < 8; ++q) op[q] = (int)(t8[q] & 0xffffffffu);
  }
}

// ---------------- Kernel 4: gather + KAN rational + BN partial sums ----------------
__global__ __launch_bounds__(256) void k_kan(const float* __restrict__ hbase,
                                             const float* __restrict__ y,
                                             const int* __restrict__ nbr,
                                             const float* __restrict__ kan_a,
                                             const float* __restrict__ kan_b,
                                             float* __restrict__ hkan,
                                             double* __restrict__ sums) {
  int f = threadIdx.x & 127;
  int half = threadIdx.x >> 7;
  int r0 = blockIdx.x * 16 + half * 8;
  float a0 = kan_a[f * 3 + 0], a1 = kan_a[f * 3 + 1], a2 = kan_a[f * 3 + 2];
  float b0 = kan_b[f * 2 + 0], b1 = kan_b[f * 2 + 1];
  float disf = (float)(1.0 / sqrt((double)(8.0f + 1e-6f)));
  float cf = disf * disf;
  double sh = 0.0, sh2 = 0.0;
  #pragma unroll
  for (int i = 0; i < 8; ++i) {
    int r = r0 + i;
    int bb = r >> 11;
    const int* np_ = nbr + (size_t)r * 8;
    float t = 0.f;
    #pragma unroll
    for (int j = 0; j < 8; ++j) {
      int m = np_[j];
      float yv = y[((size_t)(bb << 11) + m) * DD + f];
      t = fmaf(cf, yv, t);
    }
    float h = hbase[(size_t)r * DD + f] + t;
    float h2 = h * h;
    float num = (a0 + a1 * h) + a2 * h2;
    float den = 1.0f + fabsf(b0 * h + b1 * h2);
    float hk = num / (den + 1e-8f);
    hkan[(size_t)r * DD + f] = hk;
    sh += (double)hk; sh2 += (double)hk * (double)hk;
  }
  atomicAdd(&sums[f], sh);
  atomicAdd(&sums[128 + f], sh2);
}

// ---------------- Kernel 5: BN finalize + normalize ----------------
__global__ __launch_bounds__(256) void k_bn(const float* __restrict__ hkan,
                                            const double* __restrict__ sums,
                                            const float* __restrict__ gamma,
                                            const float* __restrict__ beta,
                                            float* __restrict__ out) {
  __shared__ float mn[128], sc[128], bt[128];
  int tid = threadIdx.x;
  if (tid < 128) {
    double M = (double)(BB * NN);
    double mean = sums[tid] / M;
    double var = sums[128 + tid] / M - mean * mean;
    if (var < 0.0) var = 0.0;
    mn[tid] = (float)mean;
    sc[tid] = (float)(1.0 / sqrt(var + 1e-5)) * gamma[tid];
    bt[tid] = beta[tid];
  }
  __syncthreads();
  const int total4 = BB * NN * DD / 4;
  for (int i4 = blockIdx.x * blockDim.x + threadIdx.x; i4 < total4;
       i4 += gridDim.x * blockDim.x) {
    float4 v = ((const float4*)hkan)[i4];
    int fb = (i4 * 4) & 127;
    float4 o;
    o.x = (v.x - mn[fb + 0]) * sc[fb + 0] + bt[fb + 0];
    o.y = (v.y - mn[fb + 1]) * sc[fb + 1] + bt[fb + 1];
    o.z = (v.z - mn[fb + 2]) * sc[fb + 2] + bt[fb + 2];
    o.w = (v.w - mn[fb + 3]) * sc[fb + 3] + bt[fb + 3];
    ((float4*)out)[i4] = o;
  }
}

extern "C" void kernel_launch(void* const* d_in, const int* in_sizes, int n_in,
                              void* d_out, int out_size, void* d_ws, size_t ws_size,
                              hipStream_t stream) {
  const float* x     = (const float*)d_in[0];
  const float* Ws    = (const float*)d_in[1];
  const float* Wn    = (const float*)d_in[2];
  const float* ka    = (const float*)d_in[3];
  const float* kb    = (const float*)d_in[4];
  const float* bias  = (const float*)d_in[5];
  const float* gamma = (const float*)d_in[6];
  const float* beta  = (const float*)d_in[7];
  float* out = (float*)d_out;

  char* ws = (char*)d_ws;
  float*  xx    = (float*)(ws + 0);          //  64 KB
  int*    nbr   = (int*)(ws + 65536);        // 512 KB
  double* sums  = (double*)(ws + 589824);    //   2 KB
  float*  y     = (float*)(ws + 1048576);    //   8 MB
  float*  hbase = (float*)(ws + 9437184);    //   8 MB
  float*  hkan  = (float*)(ws + 17825792);   //   8 MB

  hipMemsetAsync(sums, 0, 256 * sizeof(double), stream);
  k_xx  <<<4096, 256, 0, stream>>>(x, xx);
  k_gemm<<<256,  256, 0, stream>>>(x, Ws, Wn, bias, hbase, y);
  k_knn <<<256,  512, 0, stream>>>(x, xx, nbr);
  k_kan <<<1024, 256, 0, stream>>>(hbase, y, nbr, ka, kb, hkan, sums);
  k_bn  <<<1024, 256, 0, stream>>>(hkan, sums, gamma, beta, out);
}